// Round 10
// baseline (395.205 us; speedup 1.0000x reference)
//
#include <hip/hip_runtime.h>

#define NB 256
#define NT 4096
#define CH 16
#define W 8

typedef unsigned int u32;
typedef unsigned long long u64;
typedef int v2i __attribute__((ext_vector_type(2)));

typedef __attribute__((address_space(1))) const u32 gas_u32;
typedef __attribute__((address_space(3))) u32 las_u32;

__device__ __forceinline__ void gll16(const void* g, void* l) {
  __builtin_amdgcn_global_load_lds((gas_u32*)g, (las_u32*)l, 16, 0, 0);
}

template <int CTRL>
__device__ __forceinline__ float dppf(float x) {
  return __int_as_float(__builtin_amdgcn_update_dpp(
      0, __float_as_int(x), CTRL, 0xF, 0xF, true));
}

__device__ __forceinline__ float pl16max(float x) {
#if __has_builtin(__builtin_amdgcn_permlane16_swap)
  v2i r = __builtin_amdgcn_permlane16_swap(__float_as_int(x), __float_as_int(x),
                                           false, false);
  return fmaxf(__int_as_float(r[0]), __int_as_float(r[1]));
#else
  return fmaxf(x, __shfl_xor(x, 16, 64));
#endif
}

__device__ __forceinline__ float pl32max(float x) {
#if __has_builtin(__builtin_amdgcn_permlane32_swap)
  v2i r = __builtin_amdgcn_permlane32_swap(__float_as_int(x), __float_as_int(x),
                                           false, false);
  return fmaxf(__int_as_float(r[0]), __int_as_float(r[1]));
#else
  return fmaxf(x, __shfl_xor(x, 32, 64));
#endif
}

__global__ void __launch_bounds__(512, 2)
viterbi_k(const float* __restrict__ feats, const float* __restrict__ trans,
          float* __restrict__ out) {
  // LDS = staging only: 8 waves * 2 bufs * 16 steps * (36+6) floats = 43008 B
  __shared__ __align__(16) float s_tr[W * 2 * CH * 36];
  __shared__ __align__(16) float s_ft[W * 2 * CH * 6];

  const int wave = (int)(threadIdx.x >> 6);
  const int lane = (int)(threadIdx.x & 63);
  const int b = blockIdx.x * W + wave;
  const int g = lane >> 3;
  const int l = lane & 7;
  const int gg = (g < 6) ? g : 5;  // clamp -> duplicate-of-5 invariant
  const int jj = (l < 6) ? l : 5;
  const int offTA = gg * 6 + jj;   // A-step (odd t): i=g, j=l
  const int offTB = jj * 6 + gg;   // B-step (even t): i=l, j=g
  const int offFA = gg;
  const int offFB = jj;

  const float* trb = trans + (size_t)b * NT * 36;
  const float* ftb = feats + (size_t)b * NT * 6;
  u32* psig = (u32*)out + NB + (size_t)b * NT;  // psi staged in out's path region

  float* trsl = s_tr + wave * (2 * CH * 36);
  float* ftsl = s_ft + wave * (2 * CH * 6);

  float delta = (l == 4) ? 0.0f : -10000.0f;
  u32 mlo = 0, mhi = 0;

  auto stage = [&](int c) {
    const int buf = c & 1;
    const float* gt = trb + (size_t)c * (CH * 36);   // 576 floats
    float* lt = trsl + buf * (CH * 36);
    gll16(gt + lane * 4, lt);
    gll16(gt + 256 + lane * 4, lt + 256);
    if (lane < 16) gll16(gt + 512 + lane * 4, lt + 512);
    const float* gf = ftb + (size_t)c * (CH * 6);    // 96 floats
    float* lf = ftsl + buf * (CH * 6);
    if (lane < 24) gll16(gf + lane * 4, lf);
  };

  // consumes layout0, produces layout1 (lane (g,l) -> delta_new[g])
  auto stepA = [&](float tr, float ft, int slot) {
    float s = tr + delta;
    float m = fmaxf(s, dppf<0xB1>(s));      // xor1
    m = fmaxf(m, dppf<0x4E>(m));            // xor2
    m = fmaxf(m, dppf<0x141>(m));           // xor4 via row_half_mirror
    u64 bal = __ballot(s == m);             // bits at 8i+j
    bool cap = (lane == slot);
    mlo = cap ? (u32)bal : mlo;
    mhi = cap ? (u32)(bal >> 32) : mhi;
    delta = m + ft;
  };

  // consumes layout1, produces layout0 (lane (g,l) -> delta_new[l])
  auto stepB = [&](float tr, float ft, int slot) {
    float s = tr + delta;
    float m = fmaxf(s, dppf<0x128>(s));     // xor8 (row_ror:8)
    m = pl16max(m);                         // xor16
    m = pl32max(m);                         // xor32
    u64 bal = __ballot(s == m);             // bits at 8j+i
    bool cap = (lane == slot);
    mlo = cap ? (u32)bal : mlo;
    mhi = cap ? (u32)(bal >> 32) : mhi;
    delta = m + ft;
  };

  auto flush = [&](int base) {  // lane holds ballot of step base+lane
    u32 pA = (u32)__builtin_ctz((mlo & 63u) | 64u);
    pA |= (u32)__builtin_ctz(((mlo >> 8) & 63u) | 64u) << 3;
    pA |= (u32)__builtin_ctz(((mlo >> 16) & 63u) | 64u) << 6;
    pA |= (u32)__builtin_ctz(((mlo >> 24) & 63u) | 64u) << 9;
    pA |= (u32)__builtin_ctz((mhi & 63u) | 64u) << 12;
    pA |= (u32)__builtin_ctz(((mhi >> 8) & 63u) | 64u) << 15;
    u64 bal = ((u64)mhi << 32) | (u64)mlo;
    u32 pB = 0;
#pragma unroll
    for (int i = 0; i < 6; ++i) {
      u64 mm = (bal >> i) & 0x0000010101010101ULL;
      u32 j = (u32)(__builtin_ctzll(mm | (1ULL << 48)) >> 3);
      pB |= j << (3 * i);
    }
    u32 p = (lane & 1) ? pA : pB;
    psig[base + lane] = p;   // global store (fire-and-forget)
  };

#define LOAD8(trv, ftv, g8base)                                               \
  {                                                                           \
    _Pragma("unroll") for (int q = 0; q < 8; ++q) {                           \
      trv[q] = trp[((g8base) + q) * 36 + ((q & 1) ? offTA : offTB)];          \
      ftv[q] = ftp[((g8base) + q) * 6 + ((q & 1) ? offFA : offFB)];           \
    }                                                                         \
  }

#define STEPS8L(trv, ftv, base, ntr, nft, ng8)                                \
  {                                                                           \
    _Pragma("unroll") for (int q = 0; q < 8; ++q) {                           \
      if (q & 1) stepA(trv[q], ftv[q], ((base) + q) & 63);                    \
      else       stepB(trv[q], ftv[q], ((base) + q) & 63);                    \
      ntr[q] = trp[((ng8) + q) * 36 + ((q & 1) ? offTA : offTB)];             \
      nft[q] = ftp[((ng8) + q) * 6 + ((q & 1) ? offFA : offFB)];              \
    }                                                                         \
  }

#define STEPS8(trv, ftv, base)                                                \
  {                                                                           \
    _Pragma("unroll") for (int q = 0; q < 8; ++q) {                           \
      if (q & 1) stepA(trv[q], ftv[q], ((base) + q) & 63);                    \
      else       stepB(trv[q], ftv[q], ((base) + q) & 63);                    \
    }                                                                         \
  }

  stage(0);
  asm volatile("s_waitcnt vmcnt(0)" ::: "memory");
  stage(1);

  const float* trp;
  const float* ftp;
  float trA[8], ftA[8], trB[8], ftB[8];

  // ---- window 0 (chunks 0..3); chunk 0 skips t=0 ----
  trp = trsl; ftp = ftsl;                       // chunk 0, buf0
  LOAD8(trA, ftA, 0);
  LOAD8(trB, ftB, 8);
#pragma unroll
  for (int q = 1; q < 8; ++q) {
    if (q & 1) stepA(trA[q], ftA[q], q);
    else       stepB(trA[q], ftA[q], q);
  }
  STEPS8(trB, ftB, 8);
  asm volatile("s_waitcnt vmcnt(0)" ::: "memory");   // chunk 1, buf1
  stage(2);
  trp = trsl + CH * 36; ftp = ftsl + CH * 6;
  LOAD8(trA, ftA, 0);
  STEPS8L(trA, ftA, 16, trB, ftB, 8);
  STEPS8(trB, ftB, 24);
  asm volatile("s_waitcnt vmcnt(0)" ::: "memory");   // chunk 2, buf0
  stage(3);
  trp = trsl; ftp = ftsl;
  LOAD8(trA, ftA, 0);
  STEPS8L(trA, ftA, 32, trB, ftB, 8);
  STEPS8(trB, ftB, 40);
  asm volatile("s_waitcnt vmcnt(0)" ::: "memory");   // chunk 3, buf1
  stage(4);
  trp = trsl + CH * 36; ftp = ftsl + CH * 6;
  LOAD8(trA, ftA, 0);
  STEPS8L(trA, ftA, 48, trB, ftB, 8);
  STEPS8(trB, ftB, 56);
  flush(0);

  // ---- windows 1..63 (chunks 4w..4w+3) ----
#pragma unroll 1
  for (int w = 1; w < 64; ++w) {
    const int tb = w * 64;
    // chunk 4w (buf0): outstanding = [4 stage loads (old), flush store (new)]
    asm volatile("s_waitcnt vmcnt(1)" ::: "memory");
    stage(4 * w + 1);
    trp = trsl; ftp = ftsl;
    LOAD8(trA, ftA, 0);
    STEPS8L(trA, ftA, tb, trB, ftB, 8);
    STEPS8(trB, ftB, tb + 8);
    // chunk 4w+1 (buf1)
    asm volatile("s_waitcnt vmcnt(0)" ::: "memory");
    stage(4 * w + 2);
    trp = trsl + CH * 36; ftp = ftsl + CH * 6;
    LOAD8(trA, ftA, 0);
    STEPS8L(trA, ftA, tb + 16, trB, ftB, 8);
    STEPS8(trB, ftB, tb + 24);
    // chunk 4w+2 (buf0)
    asm volatile("s_waitcnt vmcnt(0)" ::: "memory");
    stage(4 * w + 3);
    trp = trsl; ftp = ftsl;
    LOAD8(trA, ftA, 0);
    STEPS8L(trA, ftA, tb + 32, trB, ftB, 8);
    STEPS8(trB, ftB, tb + 40);
    // chunk 4w+3 (buf1)
    asm volatile("s_waitcnt vmcnt(0)" ::: "memory");
    if (w < 63) stage(4 * w + 4);
    trp = trsl + CH * 36; ftp = ftsl + CH * 6;
    LOAD8(trA, ftA, 0);
    STEPS8L(trA, ftA, tb + 48, trB, ftB, 8);
    STEPS8(trB, ftB, tb + 56);
    flush(tb);
  }

  // ---- score + last_tag (final step is stepA -> layout1; dup groups exact)
  float sm = delta;
  sm = fmaxf(sm, dppf<0xB1>(sm));
  sm = fmaxf(sm, dppf<0x4E>(sm));
  sm = fmaxf(sm, dppf<0x141>(sm));
  sm = fmaxf(sm, dppf<0x128>(sm));
  sm = pl16max(sm);
  sm = pl32max(sm);
  u64 bs = __ballot(delta == sm);
  int last_tag = (int)((__builtin_ctzll(bs) >> 3) & 7);

  // ---- load own segment's psi into registers (own-wave written)
  asm volatile("s_waitcnt vmcnt(0)" ::: "memory");
  u32 p[64];
#pragma unroll
  for (int k = 0; k < 64; ++k) p[k] = psig[lane * 64 + k];

  // ---- per-segment backpointer-map composition (register-sourced)
  u32 Gm = 0u | (1u << 3) | (2u << 6) | (3u << 9) | (4u << 12) | (5u << 15);
#pragma unroll
  for (int k = 0; k < 64; ++k) {
    u32 pp = p[k];
    u32 ng = 0;
#pragma unroll
    for (int x = 0; x < 6; ++x) {
      u32 j = (pp >> (3 * x)) & 7;
      u32 v = (Gm >> (3 * j)) & 7;  // j in {6,7} only for unused p[0]; Gm>>18==0
      ng |= v << (3 * x);
    }
    Gm = ng;
  }

  // ---- boundary-tag chain via readlane
  int bcur = last_tag;
  int my_b = last_tag;  // lane 63
#pragma unroll 1
  for (int v = 63; v >= 1; --v) {
    u32 Gv = (u32)__builtin_amdgcn_readlane((int)Gm, v);
    bcur = (int)((Gv >> (3 * bcur)) & 7);
    my_b = (lane == v - 1) ? bcur : my_b;
  }

  // ---- per-segment walk into packed path words (registers, static idx)
  u32 pw[16];
#pragma unroll
  for (int i = 0; i < 16; ++i) pw[i] = 0;
  int tag = my_b;
  pw[15] = (u32)tag << 24;          // byte 63
#pragma unroll
  for (int k = 63; k >= 1; --k) {
    tag = (int)((p[k] >> (3 * tag)) & 7);
    pw[(k - 1) >> 2] |= (u32)tag << (8 * ((k - 1) & 3));
  }

  if (lane == 0) out[b] = sm;

  // ---- path store (overwrites psi region with floats)
  float* outp = out + NB + (size_t)b * NT;
#pragma unroll
  for (int i = 0; i < 16; ++i) {
    u32 wd = pw[i];
    float4 f;
    f.x = (float)(wd & 255u);
    f.y = (float)((wd >> 8) & 255u);
    f.z = (float)((wd >> 16) & 255u);
    f.w = (float)((wd >> 24) & 255u);
    *(float4*)(outp + (size_t)(lane * 16 + i) * 4) = f;
  }
}

extern "C" void kernel_launch(void* const* d_in, const int* in_sizes, int n_in,
                              void* d_out, int out_size, void* d_ws, size_t ws_size,
                              hipStream_t stream) {
  (void)in_sizes; (void)n_in; (void)out_size; (void)d_ws; (void)ws_size;
  const float* feats = (const float*)d_in[0];
  const float* trans = (const float*)d_in[1];
  float* out = (float*)d_out;
  hipLaunchKernelGGL(viterbi_k, dim3(NB / W), dim3(64 * W), 0, stream,
                     feats, trans, out);
}